// Round 5
// baseline (112.578 us; speedup 1.0000x reference)
//
#include <hip/hip_runtime.h>
#include <math.h>

#define GMAX 128

// ---- problem constants -----------------------------------------------------
enum {
    NP0 = 138624, NP1 = 34656, NP2 = 8664,           // positions per scale (B*g*g*3)
    PB0 = (NP0 + 255) / 256,                         // 542
    PB1 = (NP1 + 255) / 256,                         // 136
    PB2 = (NP2 + 255) / 256,                         // 34
    PBT = PB0 + PB1 + PB2,                           // 712
    NE0 = NP0 * 85, NE1 = NP1 * 85, NE2 = NP2 * 85,  // elements per scale
    NQ0 = NE0 / 4, NQ1 = NE1 / 4, NQ2 = NE2 / 4,     // float4 chunks (NEx % 4 == 0)
    SB0 = 1560, SB1 = 390, SB2 = 98,                 // stream blocks per scale
    SBT = SB0 + SB1 + SB2                            // 2048
};

__constant__ float c_aw[3][3] = {{10.f,16.f,33.f},{30.f,62.f,59.f},{116.f,156.f,373.f}};
__constant__ float c_ah[3][3] = {{13.f,30.f,23.f},{61.f,45.f,119.f},{90.f,198.f,326.f}};

// ---- helpers ---------------------------------------------------------------
__device__ __forceinline__ unsigned fkey(float f) {
    unsigned u = __float_as_uint(f);
    return (u & 0x80000000u) ? ~u : (u | 0x80000000u);
}
__device__ __forceinline__ float sigm_rn(float v) {
    return __fdiv_rn(1.0f, __fadd_rn(1.0f, expf(-v)));
}
__device__ __forceinline__ float iou_rn(float px1, float py1, float px2, float py2, float pa,
                                        float gx1, float gy1, float gx2, float gy2, float ga) {
    float iw = __fsub_rn(fminf(gx2, px2), fmaxf(gx1, px1));
    float ih = __fsub_rn(fminf(gy2, py2), fmaxf(gy1, py1));
    float inter = __fmul_rn(iw, ih);
    float uni = __fadd_rn(ga, pa);
    return __fdiv_rn(inter, __fsub_rn(uni, inter));
}
__device__ __forceinline__ void decode_box(const float* __restrict__ o, int xg, int yg, float fg,
                                           float aw, float ah,
                                           float& px, float& py, float& pw, float& ph,
                                           float& x1, float& y1, float& x2, float& y2, float& pa) {
    px = __fdiv_rn(__fadd_rn(sigm_rn(o[0]), (float)xg), fg);
    py = __fdiv_rn(__fadd_rn(sigm_rn(o[1]), (float)yg), fg);
    pw = __fdiv_rn(__fmul_rn(expf(o[2]), aw), 608.0f);
    ph = __fdiv_rn(__fmul_rn(expf(o[3]), ah), 608.0f);
    float hw = __fmul_rn(pw, 0.5f), hh = __fmul_rn(ph, 0.5f);
    x1 = __fsub_rn(px, hw); x2 = __fadd_rn(px, hw);
    y1 = __fsub_rn(py, hh); y2 = __fadd_rn(py, hh);
    pa = __fmul_rn(pw, ph);
}
__device__ __forceinline__ void stage_gt(const float* __restrict__ gtb, int G, float* sg) {
    for (int t = threadIdx.x; t < G; t += blockDim.x) {
        float cx = gtb[t*4+0], cy = gtb[t*4+1], w = gtb[t*4+2], h = gtb[t*4+3];
        float hw = __fmul_rn(w, 0.5f), hh = __fmul_rn(h, 0.5f);
        sg[t*5+0] = __fsub_rn(cx, hw);
        sg[t*5+1] = __fsub_rn(cy, hh);
        sg[t*5+2] = __fadd_rn(cx, hw);
        sg[t*5+3] = __fadd_rn(cy, hh);
        sg[t*5+4] = __fmul_rn(w, h);
    }
}

// ---- zero ws keys (argmax accumulators) ------------------------------------
__global__ __launch_bounds__(256) void k_zero(unsigned long long* __restrict__ gkeys) {
    for (int t = threadIdx.x; t < 3 * GMAX; t += 256) gkeys[t] = 0ull;
}

// ---- fused: stream (BW-bound, first) + pass1 argmax (latency-bound, tail) --
__global__ __launch_bounds__(256) void k_main(const float* __restrict__ yo0, const float* __restrict__ yt0,
                                              const float* __restrict__ yo1, const float* __restrict__ yt1,
                                              const float* __restrict__ yo2, const float* __restrict__ yt2,
                                              const float* __restrict__ gtb, int G,
                                              unsigned long long* __restrict__ gkeys,
                                              float* __restrict__ partial) {
    int bid = blockIdx.x;
    if (bid >= SBT) {
        // ---------------- pass 1: per-gt (max IoU, argmax position) --------
        __shared__ float sg[GMAX * 5];
        __shared__ unsigned long long smax[GMAX];
        int pb = bid - SBT;
        int s, lb, gd, npos;
        if (pb < PB0)            { s = 0; lb = pb;             gd = 76; npos = NP0; }
        else if (pb < PB0 + PB1) { s = 1; lb = pb - PB0;       gd = 38; npos = NP1; }
        else                     { s = 2; lb = pb - PB0 - PB1; gd = 19; npos = NP2; }
        const float* yo = (s == 0) ? yo0 : ((s == 1) ? yo1 : yo2);

        stage_gt(gtb, G, sg);
        for (int t = threadIdx.x; t < G; t += 256) smax[t] = 0ull;
        __syncthreads();

        int p = lb * 256 + threadIdx.x;
        if (p < npos) {
            int a = p % 3;
            int q = p / 3;
            int xg = q % gd;
            int yg = (q / gd) % gd;
            float px, py, pw, ph, x1, y1, x2, y2, pa;
            decode_box(yo + (size_t)p * 85, xg, yg, (float)gd, c_aw[s][a], c_ah[s][a],
                       px, py, pw, ph, x1, y1, x2, y2, pa);
            int gi = threadIdx.x % G;   // stagger LDS atomics across banks
            for (int i = 0; i < G; i++) {
                const float* sp = sg + gi * 5;
                float v = iou_rn(x1, y1, x2, y2, pa, sp[0], sp[1], sp[2], sp[3], sp[4]);
                atomicMax(&smax[gi], ((unsigned long long)fkey(v) << 32) | (unsigned)p);
                gi++; if (gi == G) gi = 0;
            }
        }
        __syncthreads();
        for (int t = threadIdx.x; t < G; t += 256)
            atomicMax(&gkeys[s * GMAX + t], smax[t]);
        return;
    }

    // ---------------- stream: BCE reduction, 2-deep prefetch ---------------
    int sbid = bid;
    int s, b0, nb, nq;
    const float* yo; const float* yt;
    if (sbid < SB0)            { s = 0; b0 = sbid;             nb = SB0; yo = yo0; yt = yt0; nq = NQ0; }
    else if (sbid < SB0 + SB1) { s = 1; b0 = sbid - SB0;       nb = SB1; yo = yo1; yt = yt1; nq = NQ1; }
    else                       { s = 2; b0 = sbid - SB0 - SB1; nb = SB2; yo = yo2; yt = yt2; nq = NQ2; }
    (void)s;

    const float4* po = reinterpret_cast<const float4*>(yo);
    const float4* pt = reinterpret_cast<const float4*>(yt);
    int stride = nb * 256;
    float bo = 0.f, om = 0.f, bc = 0.f;

    int qi = b0 * 256 + threadIdx.x;
    if (qi < nq) {
        float4 o = po[qi], t = pt[qi];
        for (;;) {
            int qn = qi + stride;
            int qc = (qn < nq) ? qn : qi;       // clamp: always-valid prefetch addr
            float4 on = po[qc], tn = pt[qc];    // issued before processing (MLP)
            {
                int r0 = (qi * 4) % 85;
                float ov[4] = {o.x, o.y, o.z, o.w};
                float tv[4] = {t.x, t.y, t.z, t.w};
#pragma unroll
                for (int j = 0; j < 4; j++) {
                    int r = r0 + j; if (r >= 85) r -= 85;
                    if (r >= 4) {
                        // x = sigmoid(raw); bce-with-logits applied to x (faithful).
                        // log(1+exp(-x)), x in (0,1): cubic interpolant (|err|<2e-4)
                        float x = __fdividef(1.f, 1.f + __expf(-ov[j]));
                        float fx = __fmaf_rn(__fmaf_rn(__fmaf_rn(-0.0088613f, x, 0.1296426f),
                                                       x, -0.5006668f), x, 0.6931472f);
                        float b = __fmaf_rn(-x, tv[j], x) + fx;
                        if (r == 4) { bo += b; om += tv[j]; }
                        else        { bc += b; }
                    }
                }
            }
            if (qn >= nq) break;
            o = on; t = tn; qi = qn;
        }
    }

    // wave -> block reduction, then ONE partial-slot write per block (no atomics)
    for (int off = 32; off > 0; off >>= 1) {
        bo += __shfl_down(bo, off);
        om += __shfl_down(om, off);
        bc += __shfl_down(bc, off);
    }
    __shared__ float sred[3][4];
    int wid = threadIdx.x >> 6, lane = threadIdx.x & 63;
    if (lane == 0) { sred[0][wid] = bo; sred[1][wid] = om; sred[2][wid] = bc; }
    __syncthreads();
    if (threadIdx.x == 0) {
        partial[sbid * 4 + 0] = sred[0][0] + sred[0][1] + sred[0][2] + sred[0][3];
        partial[sbid * 4 + 1] = sred[1][0] + sred[1][1] + sred[1][2] + sred[1][3];
        partial[sbid * 4 + 2] = sred[2][0] + sred[2][1] + sred[2][2] + sred[2][3];
    }
}

// ---- finalize: winner positions -> sparse terms; reduce partials; combine --
__global__ __launch_bounds__(256) void k_final(const float* __restrict__ yo0, const float* __restrict__ yt0,
                                               const float* __restrict__ yo1, const float* __restrict__ yt1,
                                               const float* __restrict__ yo2, const float* __restrict__ yt2,
                                               int G,
                                               const unsigned long long* __restrict__ gkeys,
                                               const float* __restrict__ partial,
                                               float* __restrict__ out) {
    __shared__ unsigned long long skey[3 * GMAX];
    __shared__ float sacc[9];        // [scale][xy, wh, sc]
    __shared__ float sred[9][4];
    int tid = threadIdx.x;

    for (int t = tid; t < 3 * GMAX; t += 256) skey[t] = gkeys[t];
    if (tid < 9) sacc[tid] = 0.f;
    __syncthreads();

    // ---- reduce stream partials (per scale) ----
    float s0b = 0.f, s0m = 0.f, s0c = 0.f;
    float s1b = 0.f, s1m = 0.f, s1c = 0.f;
    float s2b = 0.f, s2m = 0.f, s2c = 0.f;
    for (int i = tid; i < SBT; i += 256) {
        float b = partial[i * 4 + 0], m = partial[i * 4 + 1], c = partial[i * 4 + 2];
        if (i < SB0)            { s0b += b; s0m += m; s0c += c; }
        else if (i < SB0 + SB1) { s1b += b; s1m += m; s1c += c; }
        else                    { s2b += b; s2m += m; s2c += c; }
    }
    for (int off = 32; off > 0; off >>= 1) {
        s0b += __shfl_down(s0b, off); s0m += __shfl_down(s0m, off); s0c += __shfl_down(s0c, off);
        s1b += __shfl_down(s1b, off); s1m += __shfl_down(s1m, off); s1c += __shfl_down(s1c, off);
        s2b += __shfl_down(s2b, off); s2m += __shfl_down(s2m, off); s2c += __shfl_down(s2c, off);
    }
    int wid = tid >> 6, lane = tid & 63;
    if (lane == 0) {
        sred[0][wid] = s0b; sred[1][wid] = s0m; sred[2][wid] = s0c;
        sred[3][wid] = s1b; sred[4][wid] = s1m; sred[5][wid] = s1c;
        sred[6][wid] = s2b; sred[7][wid] = s2m; sred[8][wid] = s2c;
    }

    // ---- winner positions: dedupe per scale, accumulate sparse terms ----
    for (int s = 0; s < 3; s++) {
        if (tid < G) {
            unsigned long long key = skey[s * GMAX + tid];
            if (key != 0ull) {
                unsigned pos = (unsigned)(key & 0xffffffffu);
                bool uniq = true;
                for (int j = 0; j < tid; j++) {
                    unsigned long long kj = skey[s * GMAX + j];
                    if (kj != 0ull && (unsigned)(kj & 0xffffffffu) == pos) { uniq = false; break; }
                }
                if (uniq) {
                    const float* yo = (s == 0) ? yo0 : ((s == 1) ? yo1 : yo2);
                    const float* yt = (s == 0) ? yt0 : ((s == 1) ? yt1 : yt2);
                    int gd = (s == 0) ? 76 : ((s == 1) ? 38 : 19);
                    int p = (int)pos;
                    int a = p % 3;
                    int q = p / 3;
                    int xg = q % gd;
                    int yg = (q / gd) % gd;
                    float px, py, pw, ph, x1, y1, x2, y2, pa;
                    decode_box(yo + (size_t)p * 85, xg, yg, (float)gd, c_aw[s][a], c_ah[s][a],
                               px, py, pw, ph, x1, y1, x2, y2, pa);
                    const float* tp = yt + (size_t)p * 85;
                    float t0 = tp[0], t1 = tp[1], t2 = tp[2], t3 = tp[3], t4 = tp[4];
                    float bls = 2.0f - t2 * t3;
                    float dx = t0 - px, dy = t1 - py, dw = t2 - pw, dh = t3 - ph;
                    atomicAdd(&sacc[s * 3 + 0], (dx * dx + dy * dy) * bls);
                    atomicAdd(&sacc[s * 3 + 1], (dw * dw + dh * dh) * bls);
                    atomicAdd(&sacc[s * 3 + 2], 1.0f - t4);
                }
            }
        }
    }
    __syncthreads();

    if (tid == 0) {
        float bos[3], oms[3], bcs[3];
        bos[0] = sred[0][0]+sred[0][1]+sred[0][2]+sred[0][3];
        oms[0] = sred[1][0]+sred[1][1]+sred[1][2]+sred[1][3];
        bcs[0] = sred[2][0]+sred[2][1]+sred[2][2]+sred[2][3];
        bos[1] = sred[3][0]+sred[3][1]+sred[3][2]+sred[3][3];
        oms[1] = sred[4][0]+sred[4][1]+sred[4][2]+sred[4][3];
        bcs[1] = sred[5][0]+sred[5][1]+sred[5][2]+sred[5][3];
        bos[2] = sred[6][0]+sred[6][1]+sred[6][2]+sred[6][3];
        oms[2] = sred[7][0]+sred[7][1]+sred[7][2]+sred[7][3];
        bcs[2] = sred[8][0]+sred[8][1]+sred[8][2]+sred[8][3];
        const float nposf[3] = {(float)NP0, (float)NP1, (float)NP2};
        float loss = 0.f;
        for (int s = 0; s < 3; s++) {
            float xy = sacc[s * 3 + 0], wh = sacc[s * 3 + 1], sc = sacc[s * 3 + 2];
            float np_ = nposf[s];
            float ob = bos[s] / np_;                 // mean obj BCE
            float cb = bcs[s] / (np_ * 80.f);        // mean cls BCE
            loss += xy / 8.f + 0.5f * wh / 8.f + ob * (np_ - sc) / 8.f + oms[s] * cb / 8.f;
        }
        out[0] = loss;
    }
}

extern "C" void kernel_launch(void* const* d_in, const int* in_sizes, int n_in,
                              void* d_out, int out_size, void* d_ws, size_t ws_size,
                              hipStream_t stream) {
    const float *yo0, *yt0, *yo1, *yt1, *yo2, *yt2;
    if (in_sizes[0] == in_sizes[1]) {
        // setup_inputs() dict order: y_out0, y_truth0, y_out1, y_truth1, y_out2, y_truth2
        yo0 = (const float*)d_in[0]; yt0 = (const float*)d_in[1];
        yo1 = (const float*)d_in[2]; yt1 = (const float*)d_in[3];
        yo2 = (const float*)d_in[4]; yt2 = (const float*)d_in[5];
    } else {
        // reference() signature order: y_out0..2, y_truth0..2
        yo0 = (const float*)d_in[0]; yo1 = (const float*)d_in[1]; yo2 = (const float*)d_in[2];
        yt0 = (const float*)d_in[3]; yt1 = (const float*)d_in[4]; yt2 = (const float*)d_in[5];
    }
    const float* gtb = (const float*)d_in[6];
    int G = in_sizes[6] / 4;
    if (G > GMAX) G = GMAX;

    unsigned long long* gkeys = (unsigned long long*)d_ws;               // 3*GMAX u64
    float* partial = (float*)((char*)d_ws + 3 * GMAX * sizeof(unsigned long long)); // SBT*4 f32

    k_zero <<<1, 256, 0, stream>>>(gkeys);
    k_main <<<SBT + PBT, 256, 0, stream>>>(yo0, yt0, yo1, yt1, yo2, yt2, gtb, G, gkeys, partial);
    k_final<<<1, 256, 0, stream>>>(yo0, yt0, yo1, yt1, yo2, yt2, G, gkeys, partial, (float*)d_out);
}

// Round 6
// 94.850 us; speedup vs baseline: 1.1869x; 1.1869x over previous
//
#include <hip/hip_runtime.h>
#include <math.h>

#define GMAX 128

// ---- problem constants -----------------------------------------------------
enum {
    NP0 = 138624, NP1 = 34656, NP2 = 8664,           // positions per scale (B*g*g*3)
    PB0 = (NP0 + 255) / 256,                         // 542
    PB1 = (NP1 + 255) / 256,                         // 136
    PB2 = (NP2 + 255) / 256,                         // 34
    PBT = PB0 + PB1 + PB2,                           // 712
    NE0 = NP0 * 85, NE1 = NP1 * 85, NE2 = NP2 * 85,  // elements per scale
    NQ0 = NE0 / 4, NQ1 = NE1 / 4, NQ2 = NE2 / 4,     // float4 chunks (NEx % 4 == 0)
    SB0 = 1560, SB1 = 390, SB2 = 98,                 // stream blocks per scale
    SBT = SB0 + SB1 + SB2                            // 2048
};

__constant__ float c_aw[3][3] = {{10.f,16.f,33.f},{30.f,62.f,59.f},{116.f,156.f,373.f}};
__constant__ float c_ah[3][3] = {{13.f,30.f,23.f},{61.f,45.f,119.f},{90.f,198.f,326.f}};

// ---- helpers ---------------------------------------------------------------
__device__ __forceinline__ unsigned fkey(float f) {
    unsigned u = __float_as_uint(f);
    return (u & 0x80000000u) ? ~u : (u | 0x80000000u);
}
__device__ __forceinline__ float sigm_rn(float v) {
    return __fdiv_rn(1.0f, __fadd_rn(1.0f, expf(-v)));
}
__device__ __forceinline__ float iou_rn(float px1, float py1, float px2, float py2, float pa,
                                        float gx1, float gy1, float gx2, float gy2, float ga) {
    float iw = __fsub_rn(fminf(gx2, px2), fmaxf(gx1, px1));
    float ih = __fsub_rn(fminf(gy2, py2), fmaxf(gy1, py1));
    float inter = __fmul_rn(iw, ih);
    float uni = __fadd_rn(ga, pa);
    return __fdiv_rn(inter, __fsub_rn(uni, inter));
}
__device__ __forceinline__ void decode_box(const float* __restrict__ o, int xg, int yg, float fg,
                                           float aw, float ah,
                                           float& px, float& py, float& pw, float& ph,
                                           float& x1, float& y1, float& x2, float& y2, float& pa) {
    px = __fdiv_rn(__fadd_rn(sigm_rn(o[0]), (float)xg), fg);
    py = __fdiv_rn(__fadd_rn(sigm_rn(o[1]), (float)yg), fg);
    pw = __fdiv_rn(__fmul_rn(expf(o[2]), aw), 608.0f);
    ph = __fdiv_rn(__fmul_rn(expf(o[3]), ah), 608.0f);
    float hw = __fmul_rn(pw, 0.5f), hh = __fmul_rn(ph, 0.5f);
    x1 = __fsub_rn(px, hw); x2 = __fadd_rn(px, hw);
    y1 = __fsub_rn(py, hh); y2 = __fadd_rn(py, hh);
    pa = __fmul_rn(pw, ph);
}
__device__ __forceinline__ void stage_gt(const float* __restrict__ gtb, int G, float* sg) {
    for (int t = threadIdx.x; t < G; t += blockDim.x) {
        float cx = gtb[t*4+0], cy = gtb[t*4+1], w = gtb[t*4+2], h = gtb[t*4+3];
        float hw = __fmul_rn(w, 0.5f), hh = __fmul_rn(h, 0.5f);
        sg[t*5+0] = __fsub_rn(cx, hw);
        sg[t*5+1] = __fsub_rn(cy, hh);
        sg[t*5+2] = __fadd_rn(cx, hw);
        sg[t*5+3] = __fadd_rn(cy, hh);
        sg[t*5+4] = __fmul_rn(w, h);
    }
}

// ---- zero ws keys (argmax accumulators) ------------------------------------
__global__ __launch_bounds__(256) void k_zero(unsigned long long* __restrict__ gkeys) {
    for (int t = threadIdx.x; t < 3 * GMAX; t += 256) gkeys[t] = 0ull;
}

// ---- fused: pass1 argmax (first PBT blocks, interleaves) + stream (rest) ---
__global__ __launch_bounds__(256) void k_main(const float* __restrict__ yo0, const float* __restrict__ yt0,
                                              const float* __restrict__ yo1, const float* __restrict__ yt1,
                                              const float* __restrict__ yo2, const float* __restrict__ yt2,
                                              const float* __restrict__ gtb, int G,
                                              unsigned long long* __restrict__ gkeys,
                                              float* __restrict__ partial) {
    int bid = blockIdx.x;
    if (bid < PBT) {
        // ---------------- pass 1: per-gt (max IoU, argmax position) --------
        __shared__ float sg[GMAX * 5];
        __shared__ unsigned long long smax[GMAX];
        int s, lb, gd, npos;
        if (bid < PB0)            { s = 0; lb = bid;             gd = 76; npos = NP0; }
        else if (bid < PB0 + PB1) { s = 1; lb = bid - PB0;       gd = 38; npos = NP1; }
        else                      { s = 2; lb = bid - PB0 - PB1; gd = 19; npos = NP2; }
        const float* yo = (s == 0) ? yo0 : ((s == 1) ? yo1 : yo2);

        stage_gt(gtb, G, sg);
        for (int t = threadIdx.x; t < G; t += 256) smax[t] = 0ull;
        __syncthreads();

        int p = lb * 256 + threadIdx.x;
        if (p < npos) {
            int a = p % 3;
            int q = p / 3;
            int xg = q % gd;
            int yg = (q / gd) % gd;
            float px, py, pw, ph, x1, y1, x2, y2, pa;
            decode_box(yo + (size_t)p * 85, xg, yg, (float)gd, c_aw[s][a], c_ah[s][a],
                       px, py, pw, ph, x1, y1, x2, y2, pa);
            int gi = threadIdx.x % G;   // stagger LDS atomics across banks
            for (int i = 0; i < G; i++) {
                const float* sp = sg + gi * 5;
                float v = iou_rn(x1, y1, x2, y2, pa, sp[0], sp[1], sp[2], sp[3], sp[4]);
                atomicMax(&smax[gi], ((unsigned long long)fkey(v) << 32) | (unsigned)p);
                gi++; if (gi == G) gi = 0;
            }
        }
        __syncthreads();
        for (int t = threadIdx.x; t < G; t += 256)
            atomicMax(&gkeys[s * GMAX + t], smax[t]);
        return;
    }

    // ---------------- stream: BCE reduction (proven R2 grid-stride) --------
    int sbid = bid - PBT;
    int s, b0, nb, nq;
    const float* yo; const float* yt;
    if (sbid < SB0)            { s = 0; b0 = sbid;             nb = SB0; yo = yo0; yt = yt0; nq = NQ0; }
    else if (sbid < SB0 + SB1) { s = 1; b0 = sbid - SB0;       nb = SB1; yo = yo1; yt = yt1; nq = NQ1; }
    else                       { s = 2; b0 = sbid - SB0 - SB1; nb = SB2; yo = yo2; yt = yt2; nq = NQ2; }
    (void)s;

    float bo = 0.f, om = 0.f, bc = 0.f;
    for (int qi = b0 * 256 + threadIdx.x; qi < nq; qi += nb * 256) {
        int e0 = qi * 4;
        float4 o = *reinterpret_cast<const float4*>(yo + e0);
        float4 t = *reinterpret_cast<const float4*>(yt + e0);
        int r0 = e0 % 85;
        float ov[4] = {o.x, o.y, o.z, o.w};
        float tv[4] = {t.x, t.y, t.z, t.w};
#pragma unroll
        for (int j = 0; j < 4; j++) {
            int r = r0 + j; if (r >= 85) r -= 85;
            if (r >= 4) {
                // x = sigmoid(raw); bce-with-logits applied to x (faithful to ref).
                // log(1+exp(-x)) for x in (0,1) via cubic interpolant (|err|<2e-4):
                float x = __fdividef(1.f, 1.f + __expf(-ov[j]));
                float fx = __fmaf_rn(__fmaf_rn(__fmaf_rn(-0.0088613f, x, 0.1296426f),
                                               x, -0.5006668f), x, 0.6931472f);
                float b = __fmaf_rn(-x, tv[j], x) + fx;
                if (r == 4) { bo += b; om += tv[j]; }
                else        { bc += b; }
            }
        }
    }
    // wave -> block reduction, then ONE partial-slot write per block (no atomics)
    for (int off = 32; off > 0; off >>= 1) {
        bo += __shfl_down(bo, off);
        om += __shfl_down(om, off);
        bc += __shfl_down(bc, off);
    }
    __shared__ float sred[3][4];
    int wid = threadIdx.x >> 6, lane = threadIdx.x & 63;
    if (lane == 0) { sred[0][wid] = bo; sred[1][wid] = om; sred[2][wid] = bc; }
    __syncthreads();
    if (threadIdx.x == 0) {
        partial[sbid * 4 + 0] = sred[0][0] + sred[0][1] + sred[0][2] + sred[0][3];
        partial[sbid * 4 + 1] = sred[1][0] + sred[1][1] + sred[1][2] + sred[1][3];
        partial[sbid * 4 + 2] = sred[2][0] + sred[2][1] + sred[2][2] + sred[2][3];
    }
}

// ---- finalize: winner positions -> sparse terms; reduce partials; combine --
__global__ __launch_bounds__(256) void k_final(const float* __restrict__ yo0, const float* __restrict__ yt0,
                                               const float* __restrict__ yo1, const float* __restrict__ yt1,
                                               const float* __restrict__ yo2, const float* __restrict__ yt2,
                                               int G,
                                               const unsigned long long* __restrict__ gkeys,
                                               const float* __restrict__ partial,
                                               float* __restrict__ out) {
    __shared__ unsigned long long skey[3 * GMAX];
    __shared__ float sacc[9];        // [scale][xy, wh, sc]
    __shared__ float sred[9][4];
    int tid = threadIdx.x;

    for (int t = tid; t < 3 * GMAX; t += 256) skey[t] = gkeys[t];
    if (tid < 9) sacc[tid] = 0.f;
    __syncthreads();

    // ---- reduce stream partials (per scale) ----
    float s0b = 0.f, s0m = 0.f, s0c = 0.f;
    float s1b = 0.f, s1m = 0.f, s1c = 0.f;
    float s2b = 0.f, s2m = 0.f, s2c = 0.f;
    for (int i = tid; i < SBT; i += 256) {
        float b = partial[i * 4 + 0], m = partial[i * 4 + 1], c = partial[i * 4 + 2];
        if (i < SB0)            { s0b += b; s0m += m; s0c += c; }
        else if (i < SB0 + SB1) { s1b += b; s1m += m; s1c += c; }
        else                    { s2b += b; s2m += m; s2c += c; }
    }
    for (int off = 32; off > 0; off >>= 1) {
        s0b += __shfl_down(s0b, off); s0m += __shfl_down(s0m, off); s0c += __shfl_down(s0c, off);
        s1b += __shfl_down(s1b, off); s1m += __shfl_down(s1m, off); s1c += __shfl_down(s1c, off);
        s2b += __shfl_down(s2b, off); s2m += __shfl_down(s2m, off); s2c += __shfl_down(s2c, off);
    }
    int wid = tid >> 6, lane = tid & 63;
    if (lane == 0) {
        sred[0][wid] = s0b; sred[1][wid] = s0m; sred[2][wid] = s0c;
        sred[3][wid] = s1b; sred[4][wid] = s1m; sred[5][wid] = s1c;
        sred[6][wid] = s2b; sred[7][wid] = s2m; sred[8][wid] = s2c;
    }

    // ---- winner positions: dedupe per scale, accumulate sparse terms ----
    for (int s = 0; s < 3; s++) {
        if (tid < G) {
            unsigned long long key = skey[s * GMAX + tid];
            if (key != 0ull) {
                unsigned pos = (unsigned)(key & 0xffffffffu);
                bool uniq = true;
                for (int j = 0; j < tid; j++) {
                    unsigned long long kj = skey[s * GMAX + j];
                    if (kj != 0ull && (unsigned)(kj & 0xffffffffu) == pos) { uniq = false; break; }
                }
                if (uniq) {
                    const float* yo = (s == 0) ? yo0 : ((s == 1) ? yo1 : yo2);
                    const float* yt = (s == 0) ? yt0 : ((s == 1) ? yt1 : yt2);
                    int gd = (s == 0) ? 76 : ((s == 1) ? 38 : 19);
                    int p = (int)pos;
                    int a = p % 3;
                    int q = p / 3;
                    int xg = q % gd;
                    int yg = (q / gd) % gd;
                    float px, py, pw, ph, x1, y1, x2, y2, pa;
                    decode_box(yo + (size_t)p * 85, xg, yg, (float)gd, c_aw[s][a], c_ah[s][a],
                               px, py, pw, ph, x1, y1, x2, y2, pa);
                    const float* tp = yt + (size_t)p * 85;
                    float t0 = tp[0], t1 = tp[1], t2 = tp[2], t3 = tp[3], t4 = tp[4];
                    float bls = 2.0f - t2 * t3;
                    float dx = t0 - px, dy = t1 - py, dw = t2 - pw, dh = t3 - ph;
                    atomicAdd(&sacc[s * 3 + 0], (dx * dx + dy * dy) * bls);
                    atomicAdd(&sacc[s * 3 + 1], (dw * dw + dh * dh) * bls);
                    atomicAdd(&sacc[s * 3 + 2], 1.0f - t4);
                }
            }
        }
    }
    __syncthreads();

    if (tid == 0) {
        float bos[3], oms[3], bcs[3];
        bos[0] = sred[0][0]+sred[0][1]+sred[0][2]+sred[0][3];
        oms[0] = sred[1][0]+sred[1][1]+sred[1][2]+sred[1][3];
        bcs[0] = sred[2][0]+sred[2][1]+sred[2][2]+sred[2][3];
        bos[1] = sred[3][0]+sred[3][1]+sred[3][2]+sred[3][3];
        oms[1] = sred[4][0]+sred[4][1]+sred[4][2]+sred[4][3];
        bcs[1] = sred[5][0]+sred[5][1]+sred[5][2]+sred[5][3];
        bos[2] = sred[6][0]+sred[6][1]+sred[6][2]+sred[6][3];
        oms[2] = sred[7][0]+sred[7][1]+sred[7][2]+sred[7][3];
        bcs[2] = sred[8][0]+sred[8][1]+sred[8][2]+sred[8][3];
        const float nposf[3] = {(float)NP0, (float)NP1, (float)NP2};
        float loss = 0.f;
        for (int s = 0; s < 3; s++) {
            float xy = sacc[s * 3 + 0], wh = sacc[s * 3 + 1], sc = sacc[s * 3 + 2];
            float np_ = nposf[s];
            float ob = bos[s] / np_;                 // mean obj BCE
            float cb = bcs[s] / (np_ * 80.f);        // mean cls BCE
            loss += xy / 8.f + 0.5f * wh / 8.f + ob * (np_ - sc) / 8.f + oms[s] * cb / 8.f;
        }
        out[0] = loss;
    }
}

extern "C" void kernel_launch(void* const* d_in, const int* in_sizes, int n_in,
                              void* d_out, int out_size, void* d_ws, size_t ws_size,
                              hipStream_t stream) {
    const float *yo0, *yt0, *yo1, *yt1, *yo2, *yt2;
    if (in_sizes[0] == in_sizes[1]) {
        // setup_inputs() dict order: y_out0, y_truth0, y_out1, y_truth1, y_out2, y_truth2
        yo0 = (const float*)d_in[0]; yt0 = (const float*)d_in[1];
        yo1 = (const float*)d_in[2]; yt1 = (const float*)d_in[3];
        yo2 = (const float*)d_in[4]; yt2 = (const float*)d_in[5];
    } else {
        // reference() signature order: y_out0..2, y_truth0..2
        yo0 = (const float*)d_in[0]; yo1 = (const float*)d_in[1]; yo2 = (const float*)d_in[2];
        yt0 = (const float*)d_in[3]; yt1 = (const float*)d_in[4]; yt2 = (const float*)d_in[5];
    }
    const float* gtb = (const float*)d_in[6];
    int G = in_sizes[6] / 4;
    if (G > GMAX) G = GMAX;

    unsigned long long* gkeys = (unsigned long long*)d_ws;               // 3*GMAX u64
    float* partial = (float*)((char*)d_ws + 3 * GMAX * sizeof(unsigned long long)); // SBT*4 f32

    k_zero <<<1, 256, 0, stream>>>(gkeys);
    k_main <<<PBT + SBT, 256, 0, stream>>>(yo0, yt0, yo1, yt1, yo2, yt2, gtb, G, gkeys, partial);
    k_final<<<1, 256, 0, stream>>>(yo0, yt0, yo1, yt1, yo2, yt2, G, gkeys, partial, (float*)d_out);
}

// Round 7
// 68.958 us; speedup vs baseline: 1.6326x; 1.3755x over previous
//
#include <hip/hip_runtime.h>
#include <math.h>

#define GMAX 128

// ---- problem constants -----------------------------------------------------
enum {
    NP0 = 138624, NP1 = 34656, NP2 = 8664,           // positions per scale (B*g*g*3)
    PB0 = (NP0 + 255) / 256,                         // 542
    PB1 = (NP1 + 255) / 256,                         // 136
    PB2 = (NP2 + 255) / 256,                         // 34
    PBT = PB0 + PB1 + PB2,                           // 712
    NE0 = NP0 * 85, NE1 = NP1 * 85, NE2 = NP2 * 85,  // elements per scale
    NQ0 = NE0 / 4, NQ1 = NE1 / 4, NQ2 = NE2 / 4,     // float4 chunks (NEx % 4 == 0)
    SB0 = 1560, SB1 = 390, SB2 = 98,                 // stream blocks per scale
    SBT = SB0 + SB1 + SB2                            // 2048
};

__constant__ float c_aw[3][3] = {{10.f,16.f,33.f},{30.f,62.f,59.f},{116.f,156.f,373.f}};
__constant__ float c_ah[3][3] = {{13.f,30.f,23.f},{61.f,45.f,119.f},{90.f,198.f,326.f}};

// ---- helpers ---------------------------------------------------------------
__device__ __forceinline__ unsigned fkey(float f) {
    unsigned u = __float_as_uint(f);
    return (u & 0x80000000u) ? ~u : (u | 0x80000000u);
}
__device__ __forceinline__ float sigm_rn(float v) {
    return __fdiv_rn(1.0f, __fadd_rn(1.0f, expf(-v)));
}
__device__ __forceinline__ float iou_rn(float px1, float py1, float px2, float py2, float pa,
                                        float gx1, float gy1, float gx2, float gy2, float ga) {
    float iw = __fsub_rn(fminf(gx2, px2), fmaxf(gx1, px1));
    float ih = __fsub_rn(fminf(gy2, py2), fmaxf(gy1, py1));
    float inter = __fmul_rn(iw, ih);
    float uni = __fadd_rn(ga, pa);
    return __fdiv_rn(inter, __fsub_rn(uni, inter));
}
__device__ __forceinline__ void decode_box(const float* __restrict__ o, int xg, int yg, float fg,
                                           float aw, float ah,
                                           float& px, float& py, float& pw, float& ph,
                                           float& x1, float& y1, float& x2, float& y2, float& pa) {
    px = __fdiv_rn(__fadd_rn(sigm_rn(o[0]), (float)xg), fg);
    py = __fdiv_rn(__fadd_rn(sigm_rn(o[1]), (float)yg), fg);
    pw = __fdiv_rn(__fmul_rn(expf(o[2]), aw), 608.0f);
    ph = __fdiv_rn(__fmul_rn(expf(o[3]), ah), 608.0f);
    float hw = __fmul_rn(pw, 0.5f), hh = __fmul_rn(ph, 0.5f);
    x1 = __fsub_rn(px, hw); x2 = __fadd_rn(px, hw);
    y1 = __fsub_rn(py, hh); y2 = __fadd_rn(py, hh);
    pa = __fmul_rn(pw, ph);
}
__device__ __forceinline__ void stage_gt(const float* __restrict__ gtb, int G, float* sg) {
    for (int t = threadIdx.x; t < G; t += blockDim.x) {
        float cx = gtb[t*4+0], cy = gtb[t*4+1], w = gtb[t*4+2], h = gtb[t*4+3];
        float hw = __fmul_rn(w, 0.5f), hh = __fmul_rn(h, 0.5f);
        sg[t*5+0] = __fsub_rn(cx, hw);
        sg[t*5+1] = __fsub_rn(cy, hh);
        sg[t*5+2] = __fadd_rn(cx, hw);
        sg[t*5+3] = __fadd_rn(cy, hh);
        sg[t*5+4] = __fmul_rn(w, h);
    }
}

// ---- zero ws keys (argmax accumulators) ------------------------------------
__global__ __launch_bounds__(256) void k_zero(unsigned long long* __restrict__ gkeys) {
    for (int t = threadIdx.x; t < 3 * GMAX; t += 256) gkeys[t] = 0ull;
}

// ---- fused: pass1 argmax (first PBT blocks, interleaves) + stream (rest) ---
__global__ __launch_bounds__(256) void k_main(const float* __restrict__ yo0, const float* __restrict__ yt0,
                                              const float* __restrict__ yo1, const float* __restrict__ yt1,
                                              const float* __restrict__ yo2, const float* __restrict__ yt2,
                                              const float* __restrict__ gtb, int G,
                                              unsigned long long* __restrict__ gkeys,
                                              float* __restrict__ partial) {
    int bid = blockIdx.x;
    if (bid < PBT) {
        // ---------------- pass 1: per-gt (max IoU, argmax position) --------
        __shared__ float sg[GMAX * 5];
        __shared__ unsigned long long smax[GMAX];
        int s, lb, gd, npos;
        if (bid < PB0)            { s = 0; lb = bid;             gd = 76; npos = NP0; }
        else if (bid < PB0 + PB1) { s = 1; lb = bid - PB0;       gd = 38; npos = NP1; }
        else                      { s = 2; lb = bid - PB0 - PB1; gd = 19; npos = NP2; }
        const float* yo = (s == 0) ? yo0 : ((s == 1) ? yo1 : yo2);

        stage_gt(gtb, G, sg);
        for (int t = threadIdx.x; t < G; t += 256) smax[t] = 0ull;
        __syncthreads();

        int p = lb * 256 + threadIdx.x;
        if (p < npos) {
            int a = p % 3;
            int q = p / 3;
            int xg = q % gd;
            int yg = (q / gd) % gd;
            float px, py, pw, ph, x1, y1, x2, y2, pa;
            decode_box(yo + (size_t)p * 85, xg, yg, (float)gd, c_aw[s][a], c_ah[s][a],
                       px, py, pw, ph, x1, y1, x2, y2, pa);
            int gi = threadIdx.x % G;   // stagger LDS atomics across banks
            for (int i = 0; i < G; i++) {
                const float* sp = sg + gi * 5;
                float v = iou_rn(x1, y1, x2, y2, pa, sp[0], sp[1], sp[2], sp[3], sp[4]);
                atomicMax(&smax[gi], ((unsigned long long)fkey(v) << 32) | (unsigned)p);
                gi++; if (gi == G) gi = 0;
            }
        }
        __syncthreads();
        for (int t = threadIdx.x; t < G; t += 256)
            atomicMax(&gkeys[s * GMAX + t], smax[t]);
        return;
    }

    // ---------------- stream: BCE reduction (R2 grid-stride, unroll 2) -----
    int sbid = bid - PBT;
    int s, b0, nb, nq;
    const float* yo; const float* yt;
    if (sbid < SB0)            { s = 0; b0 = sbid;             nb = SB0; yo = yo0; yt = yt0; nq = NQ0; }
    else if (sbid < SB0 + SB1) { s = 1; b0 = sbid - SB0;       nb = SB1; yo = yo1; yt = yt1; nq = NQ1; }
    else                       { s = 2; b0 = sbid - SB0 - SB1; nb = SB2; yo = yo2; yt = yt2; nq = NQ2; }
    (void)s;

    float bo = 0.f, om = 0.f, bc = 0.f;
#pragma unroll 2
    for (int qi = b0 * 256 + threadIdx.x; qi < nq; qi += nb * 256) {
        int e0 = qi * 4;
        float4 o = *reinterpret_cast<const float4*>(yo + e0);
        float4 t = *reinterpret_cast<const float4*>(yt + e0);
        int r0 = e0 % 85;
        float ov[4] = {o.x, o.y, o.z, o.w};
        float tv[4] = {t.x, t.y, t.z, t.w};
#pragma unroll
        for (int j = 0; j < 4; j++) {
            int r = r0 + j; if (r >= 85) r -= 85;
            if (r >= 4) {
                // x = sigmoid(raw); bce-with-logits applied to x (faithful to ref).
                // log(1+exp(-x)) for x in (0,1) via cubic interpolant (|err|<2e-4):
                float x = __fdividef(1.f, 1.f + __expf(-ov[j]));
                float fx = __fmaf_rn(__fmaf_rn(__fmaf_rn(-0.0088613f, x, 0.1296426f),
                                               x, -0.5006668f), x, 0.6931472f);
                float b = __fmaf_rn(-x, tv[j], x) + fx;
                if (r == 4) { bo += b; om += tv[j]; }
                else        { bc += b; }
            }
        }
    }
    // wave -> block reduction, then ONE partial-slot write per block (no atomics)
    for (int off = 32; off > 0; off >>= 1) {
        bo += __shfl_down(bo, off);
        om += __shfl_down(om, off);
        bc += __shfl_down(bc, off);
    }
    __shared__ float sred[3][4];
    int wid = threadIdx.x >> 6, lane = threadIdx.x & 63;
    if (lane == 0) { sred[0][wid] = bo; sred[1][wid] = om; sred[2][wid] = bc; }
    __syncthreads();
    if (threadIdx.x == 0) {
        partial[sbid * 4 + 0] = sred[0][0] + sred[0][1] + sred[0][2] + sred[0][3];
        partial[sbid * 4 + 1] = sred[1][0] + sred[1][1] + sred[1][2] + sred[1][3];
        partial[sbid * 4 + 2] = sred[2][0] + sred[2][1] + sred[2][2] + sred[2][3];
    }
}

// ---- finalize: winner positions -> sparse terms; reduce partials; combine --
__global__ __launch_bounds__(256) void k_final(const float* __restrict__ yo0, const float* __restrict__ yt0,
                                               const float* __restrict__ yo1, const float* __restrict__ yt1,
                                               const float* __restrict__ yo2, const float* __restrict__ yt2,
                                               int G,
                                               const unsigned long long* __restrict__ gkeys,
                                               const float* __restrict__ partial,
                                               float* __restrict__ out) {
    __shared__ unsigned spos[3 * GMAX];  // winner position per (scale, gt); ~0u = none
    __shared__ float sacc[9];            // [scale][xy, wh, sc]
    __shared__ float sred[9][4];
    int tid = threadIdx.x;

    for (int t = tid; t < 3 * GMAX; t += 256) {
        unsigned long long k = gkeys[t];
        spos[t] = (k == 0ull) ? 0xffffffffu : (unsigned)(k & 0xffffffffu);
    }
    if (tid < 9) sacc[tid] = 0.f;
    __syncthreads();

    // ---- reduce stream partials (per scale) ----
    float s0b = 0.f, s0m = 0.f, s0c = 0.f;
    float s1b = 0.f, s1m = 0.f, s1c = 0.f;
    float s2b = 0.f, s2m = 0.f, s2c = 0.f;
    for (int i = tid; i < SBT; i += 256) {
        float b = partial[i * 4 + 0], m = partial[i * 4 + 1], c = partial[i * 4 + 2];
        if (i < SB0)            { s0b += b; s0m += m; s0c += c; }
        else if (i < SB0 + SB1) { s1b += b; s1m += m; s1c += c; }
        else                    { s2b += b; s2m += m; s2c += c; }
    }
    for (int off = 32; off > 0; off >>= 1) {
        s0b += __shfl_down(s0b, off); s0m += __shfl_down(s0m, off); s0c += __shfl_down(s0c, off);
        s1b += __shfl_down(s1b, off); s1m += __shfl_down(s1m, off); s1c += __shfl_down(s1c, off);
        s2b += __shfl_down(s2b, off); s2m += __shfl_down(s2m, off); s2c += __shfl_down(s2c, off);
    }
    int wid = tid >> 6, lane = tid & 63;
    if (lane == 0) {
        sred[0][wid] = s0b; sred[1][wid] = s0m; sred[2][wid] = s0c;
        sred[3][wid] = s1b; sred[4][wid] = s1m; sred[5][wid] = s1c;
        sred[6][wid] = s2b; sred[7][wid] = s2m; sred[8][wid] = s2c;
    }

    // ---- winners: all scales in parallel; branch-free pipelined uniq scan ----
    for (int t = tid; t < 3 * GMAX; t += 256) {
        unsigned pos = spos[t];
        if (pos != 0xffffffffu) {
            int s = t >> 7;          // GMAX == 128
            int gi = t & (GMAX - 1);
            int base = s << 7;
            bool uniq = true;
            for (int j = 0; j < gi; j++)         // no break -> independent LDS reads
                uniq = uniq && (spos[base + j] != pos);
            if (uniq) {
                const float* yo = (s == 0) ? yo0 : ((s == 1) ? yo1 : yo2);
                const float* yt = (s == 0) ? yt0 : ((s == 1) ? yt1 : yt2);
                int gd = (s == 0) ? 76 : ((s == 1) ? 38 : 19);
                int p = (int)pos;
                int a = p % 3;
                int q = p / 3;
                int xg = q % gd;
                int yg = (q / gd) % gd;
                float px, py, pw, ph, x1, y1, x2, y2, pa;
                decode_box(yo + (size_t)p * 85, xg, yg, (float)gd, c_aw[s][a], c_ah[s][a],
                           px, py, pw, ph, x1, y1, x2, y2, pa);
                const float* tp = yt + (size_t)p * 85;
                float t0 = tp[0], t1 = tp[1], t2 = tp[2], t3 = tp[3], t4 = tp[4];
                float bls = 2.0f - t2 * t3;
                float dx = t0 - px, dy = t1 - py, dw = t2 - pw, dh = t3 - ph;
                atomicAdd(&sacc[s * 3 + 0], (dx * dx + dy * dy) * bls);
                atomicAdd(&sacc[s * 3 + 1], (dw * dw + dh * dh) * bls);
                atomicAdd(&sacc[s * 3 + 2], 1.0f - t4);
            }
        }
    }
    __syncthreads();

    if (tid == 0) {
        float bos[3], oms[3], bcs[3];
        bos[0] = sred[0][0]+sred[0][1]+sred[0][2]+sred[0][3];
        oms[0] = sred[1][0]+sred[1][1]+sred[1][2]+sred[1][3];
        bcs[0] = sred[2][0]+sred[2][1]+sred[2][2]+sred[2][3];
        bos[1] = sred[3][0]+sred[3][1]+sred[3][2]+sred[3][3];
        oms[1] = sred[4][0]+sred[4][1]+sred[4][2]+sred[4][3];
        bcs[1] = sred[5][0]+sred[5][1]+sred[5][2]+sred[5][3];
        bos[2] = sred[6][0]+sred[6][1]+sred[6][2]+sred[6][3];
        oms[2] = sred[7][0]+sred[7][1]+sred[7][2]+sred[7][3];
        bcs[2] = sred[8][0]+sred[8][1]+sred[8][2]+sred[8][3];
        const float nposf[3] = {(float)NP0, (float)NP1, (float)NP2};
        float loss = 0.f;
        for (int s = 0; s < 3; s++) {
            float xy = sacc[s * 3 + 0], wh = sacc[s * 3 + 1], sc = sacc[s * 3 + 2];
            float np_ = nposf[s];
            float ob = bos[s] / np_;                 // mean obj BCE
            float cb = bcs[s] / (np_ * 80.f);        // mean cls BCE
            loss += xy / 8.f + 0.5f * wh / 8.f + ob * (np_ - sc) / 8.f + oms[s] * cb / 8.f;
        }
        out[0] = loss;
    }
}

extern "C" void kernel_launch(void* const* d_in, const int* in_sizes, int n_in,
                              void* d_out, int out_size, void* d_ws, size_t ws_size,
                              hipStream_t stream) {
    const float *yo0, *yt0, *yo1, *yt1, *yo2, *yt2;
    if (in_sizes[0] == in_sizes[1]) {
        // setup_inputs() dict order: y_out0, y_truth0, y_out1, y_truth1, y_out2, y_truth2
        yo0 = (const float*)d_in[0]; yt0 = (const float*)d_in[1];
        yo1 = (const float*)d_in[2]; yt1 = (const float*)d_in[3];
        yo2 = (const float*)d_in[4]; yt2 = (const float*)d_in[5];
    } else {
        // reference() signature order: y_out0..2, y_truth0..2
        yo0 = (const float*)d_in[0]; yo1 = (const float*)d_in[1]; yo2 = (const float*)d_in[2];
        yt0 = (const float*)d_in[3]; yt1 = (const float*)d_in[4]; yt2 = (const float*)d_in[5];
    }
    const float* gtb = (const float*)d_in[6];
    int G = in_sizes[6] / 4;
    if (G > GMAX) G = GMAX;

    unsigned long long* gkeys = (unsigned long long*)d_ws;               // 3*GMAX u64
    float* partial = (float*)((char*)d_ws + 3 * GMAX * sizeof(unsigned long long)); // SBT*4 f32

    k_zero <<<1, 256, 0, stream>>>(gkeys);
    k_main <<<PBT + SBT, 256, 0, stream>>>(yo0, yt0, yo1, yt1, yo2, yt2, gtb, G, gkeys, partial);
    k_final<<<1, 256, 0, stream>>>(yo0, yt0, yo1, yt1, yo2, yt2, G, gkeys, partial, (float*)d_out);
}